// Round 20
// baseline (55.333 us; speedup 1.0000x reference)
//
#include <hip/hip_runtime.h>
#include <hip/hip_bf16.h>

// Problem constants
#define HSZ 32
#define HP1 33
#define M3 35937            // 33^3 (flattened j,k,l)
#define M3P2 35968          // padded to 1124*32
#define TI_STRIDE 1149984   // 33^3 * 32 floats (stride of T over i)
#define TIB ((size_t)TI_STRIDE * 4)
#define NBLK 1124           // one wave per block, 32 m's per block
#define DEPTH 6             // LDS ring slots (rows in flight, 4KB each)

// ws layout (bytes): a0T @ 0 ; D @ 8192 (32*35968*4)
#define OFF_A0T   0
#define OFF_D     8192

typedef short bf16x8 __attribute__((ext_vector_type(8)));
typedef float f32x16 __attribute__((ext_vector_type(16)));

__device__ inline short f2bf(float f) {
  __hip_bfloat16 h = __float2bfloat16(f);  // RTNE; pairs into v_cvt_pk_bf16_f32
  return __builtin_bit_cast(short, h);
}

// Prologue: D[b][m]=a1*a2*a3 (0 in pad), a0T[i][b], zero d_out (4 KB).
__global__ __launch_bounds__(256) void k_pre(const float* __restrict__ nh,
                                             float* __restrict__ a0T,
                                             float* __restrict__ D,
                                             float* __restrict__ out) {
  const int b = blockIdx.y;
  const int m = blockIdx.x * 256 + threadIdx.x;
  if (m < M3P2) {
    float v = 0.f;
    if (m < M3) {
      const int j = m / 1089;
      const int r = m - j * 1089;
      const int k = r / 33;
      const int l = r - k * 33;
      const float a1 = (j < HSZ) ? nh[(b * 4 + 1) * HSZ + j] : 1.0f;
      const float a2 = (k < HSZ) ? nh[(b * 4 + 2) * HSZ + k] : 1.0f;
      const float a3 = (l < HSZ) ? nh[(b * 4 + 3) * HSZ + l] : 1.0f;
      v = a1 * a2 * a3;
    }
    D[(size_t)b * M3P2 + m] = v;
  }
  if (blockIdx.x == 0 && threadIdx.x < HP1) {
    const int i = threadIdx.x;
    a0T[i * 32 + b] = (i < HSZ) ? nh[(b * 4 + 0) * HSZ + i] : 1.0f;
  }
  if (blockIdx.x == 1 && b == 0) {
    ((float4*)out)[threadIdx.x] = make_float4(0.f, 0.f, 0.f, 0.f);
  }
}

// Main (r19 loop verbatim): one wave per block; block owns 32 m's. 6-slot
// LDS DMA ring (4KB rows), counted vmcnt(20); 2 MFMAs per row into one acc.
// Epilogue: 16 atomicAdds per wave DIRECTLY into d_out (17.6 contenders per
// address -- same contention as the old NT=64 tiles, but no k_red dispatch).
__global__ __launch_bounds__(64) void k_main(const float* __restrict__ T,
                                             const float* __restrict__ a0T,
                                             const float* __restrict__ D,
                                             float* __restrict__ out) {
  __shared__ float lds[DEPTH * 1024];  // 6 slots x 4096 B
  const int blk = blockIdx.x;
  const int m0 = blk * 32;
  const int l = (int)threadIdx.x;  // 0..63
  const int bo = l & 31;           // A row (b) / B col (o)
  const int g = l >> 5;            // k-group: k = 8*g + e

  // A-side D fragments: half0 = D[bo][m0+8g+e], half1 = D[bo][m0+16+8g+e]
  const float* dp = D + (size_t)bo * M3P2 + m0 + 8 * g;
  float df0[8], df1[8];
  *(float4*)(df0)     = *(const float4*)(dp);
  *(float4*)(df0 + 4) = *(const float4*)(dp + 4);
  *(float4*)(df1)     = *(const float4*)(dp + 16);
  *(float4*)(df1 + 4) = *(const float4*)(dp + 20);

  // a0 preload into registers
  float a0v[HP1];
#pragma unroll
  for (int i = 0; i < HP1; ++i) a0v[i] = a0T[i * 32 + bo];

  // Drain prologue loads BEFORE the DMA stream (pure vmcnt accounting).
  {
    float s = 0.f;
#pragma unroll
    for (int e = 0; e < 8; ++e) s += df0[e] + df1[e];
#pragma unroll
    for (int i = 0; i < HP1; ++i) s += a0v[i];
    asm volatile("" :: "v"(s) : "memory");
  }

  // Per-lane DMA source byte offsets: op q covers row floats [q*256+4l, +4)
  const int mrel = l >> 3;
  size_t src[4];
#pragma unroll
  for (int q = 0; q < 4; ++q) {
    const bool valid = (m0 + 8 * q + mrel) < M3;
    src[q] = valid ? ((size_t)(m0 * 32 + q * 256 + l * 4) * 4) : 0;
  }
  const char* Tb = (const char*)T;

#define ISSUE(row_, slot_)                                                    \
  {                                                                           \
    _Pragma("unroll")                                                         \
    for (int q = 0; q < 4; ++q) {                                             \
      __builtin_amdgcn_global_load_lds(                                       \
          (const __attribute__((address_space(1))) void*)(                    \
              Tb + (size_t)(row_)*TIB + src[q]),                              \
          (__attribute__((address_space(3))) void*)(                          \
              &lds[(slot_)*1024 + q * 256]),                                  \
          16, 0, 0);                                                          \
    }                                                                         \
  }

  // Fill the ring: 24 DMA ops in flight.
  ISSUE(0, 0) ISSUE(1, 1) ISSUE(2, 2) ISSUE(3, 3) ISSUE(4, 4) ISSUE(5, 5)

  f32x16 acc = {};

#define STEP(i_, vm_, doIssue_)                                               \
  {                                                                           \
    asm volatile("s_waitcnt vmcnt(" #vm_ ")" ::: "memory");                   \
    __builtin_amdgcn_sched_barrier(0);                                        \
    float tv0[8], tv1[8];                                                     \
    _Pragma("unroll")                                                         \
    for (int e = 0; e < 8; ++e) {                                             \
      tv0[e] = lds[((i_) % DEPTH) * 1024 + (8 * g + e) * 32 + bo];            \
      tv1[e] = lds[((i_) % DEPTH) * 1024 + 512 + (8 * g + e) * 32 + bo];      \
    }                                                                         \
    asm volatile("s_waitcnt lgkmcnt(0)" ::: "memory");                        \
    if (doIssue_) ISSUE((i_) + DEPTH, (i_) % DEPTH)                           \
    bf16x8 af0, bf0, af1, bf1;                                                \
    _Pragma("unroll")                                                         \
    for (int e = 0; e < 8; ++e) {                                             \
      af0[e] = f2bf(a0v[i_] * df0[e]);                                        \
      bf0[e] = f2bf(tv0[e]);                                                  \
      af1[e] = f2bf(a0v[i_] * df1[e]);                                        \
      bf1[e] = f2bf(tv1[e]);                                                  \
    }                                                                         \
    acc = __builtin_amdgcn_mfma_f32_32x32x16_bf16(af0, bf0, acc, 0, 0, 0);    \
    acc = __builtin_amdgcn_mfma_f32_32x32x16_bf16(af1, bf1, acc, 0, 0, 0);    \
  }

  // 33 steps: steady vmcnt(20) while issuing (i<=26), then drain.
  STEP(0, 20, 1)  STEP(1, 20, 1)  STEP(2, 20, 1)  STEP(3, 20, 1)
  STEP(4, 20, 1)  STEP(5, 20, 1)  STEP(6, 20, 1)  STEP(7, 20, 1)
  STEP(8, 20, 1)  STEP(9, 20, 1)  STEP(10, 20, 1) STEP(11, 20, 1)
  STEP(12, 20, 1) STEP(13, 20, 1) STEP(14, 20, 1) STEP(15, 20, 1)
  STEP(16, 20, 1) STEP(17, 20, 1) STEP(18, 20, 1) STEP(19, 20, 1)
  STEP(20, 20, 1) STEP(21, 20, 1) STEP(22, 20, 1) STEP(23, 20, 1)
  STEP(24, 20, 1) STEP(25, 20, 1) STEP(26, 20, 1) STEP(27, 20, 0)
  STEP(28, 16, 0) STEP(29, 12, 0) STEP(30, 8, 0)  STEP(31, 4, 0)
  STEP(32, 0, 0)
#undef STEP
#undef ISSUE

  // Direct atomic accumulate into d_out (fire-and-forget; no exit wait).
  // C/D layout (m74/m101): col=lane&31, row=(r&3)+8*(r>>2)+4*(lane>>5)
#pragma unroll
  for (int r = 0; r < 16; ++r) {
    const int brow = (r & 3) + 8 * (r >> 2) + 4 * g;
    atomicAdd(out + brow * 32 + bo, acc[r]);
  }
}

extern "C" void kernel_launch(void* const* d_in, const int* in_sizes, int n_in,
                              void* d_out, int out_size, void* d_ws, size_t ws_size,
                              hipStream_t stream) {
  const float* nh = (const float*)d_in[0];  // [32,4,32]
  const float* T  = (const float*)d_in[1];  // [33,33,33,33,32]
  float* out = (float*)d_out;               // [32,32] fp32
  char* ws = (char*)d_ws;
  float* a0T   = (float*)(ws + OFF_A0T);
  float* D     = (float*)(ws + OFF_D);

  k_pre<<<dim3(141, 32), 256, 0, stream>>>(nh, a0T, D, out);
  k_main<<<NBLK, 64, 0, stream>>>(T, a0T, D, out);
}

// Round 21
// 39.905 us; speedup vs baseline: 1.3866x; 1.3866x over previous
//
#include <hip/hip_runtime.h>
#include <hip/hip_bf16.h>

// Problem constants
#define HSZ 32
#define HP1 33
#define M3 35937            // 33^3 (flattened j,k,l)
#define M3P2 35968          // padded to 562*64
#define TI_STRIDE 1149984   // 33^3 * 32 floats (stride of T over i)
#define TIB ((size_t)TI_STRIDE * 4)
#define NBLK 562            // one wave per block, 64 m's per block
#define NT 64               // partial output tiles (contention 562/64 ~ 9)
#define DEPTH 6             // LDS ring slots (8KB each -> 48KB)

// ws layout (bytes): a0T @ 0 ; D @ 8192 (32*35968*4) ; tiles @ 4612096
#define OFF_A0T   0
#define OFF_D     8192
#define OFF_TILES 4612096

typedef short bf16x8 __attribute__((ext_vector_type(8)));
typedef float f32x16 __attribute__((ext_vector_type(16)));

__device__ inline short f2bf(float f) {
  __hip_bfloat16 h = __float2bfloat16(f);  // RTNE; pairs into v_cvt_pk_bf16_f32
  return __builtin_bit_cast(short, h);
}

// Prologue (r19 verbatim): D, a0T, zero tiles.
__global__ __launch_bounds__(256) void k_pre(const float* __restrict__ nh,
                                             float* __restrict__ a0T,
                                             float* __restrict__ D,
                                             float* __restrict__ tiles) {
  const int b = blockIdx.y;
  const int m = blockIdx.x * 256 + threadIdx.x;
  if (m < M3P2) {
    float v = 0.f;
    if (m < M3) {
      const int j = m / 1089;
      const int r = m - j * 1089;
      const int k = r / 33;
      const int l = r - k * 33;
      const float a1 = (j < HSZ) ? nh[(b * 4 + 1) * HSZ + j] : 1.0f;
      const float a2 = (k < HSZ) ? nh[(b * 4 + 2) * HSZ + k] : 1.0f;
      const float a3 = (l < HSZ) ? nh[(b * 4 + 3) * HSZ + l] : 1.0f;
      v = a1 * a2 * a3;
    }
    D[(size_t)b * M3P2 + m] = v;
  }
  if (blockIdx.x == 0 && threadIdx.x < HP1) {
    const int i = threadIdx.x;
    a0T[i * 32 + b] = (i < HSZ) ? nh[(b * 4 + 0) * HSZ + i] : 1.0f;
  }
  if (b == 1 && blockIdx.x < 64) {
    ((float4*)tiles)[blockIdx.x * 256 + threadIdx.x] =
        make_float4(0.f, 0.f, 0.f, 0.f);
  }
}

// Main: one wave per block; block owns 64 m's (8KB slab per i-row).
// 6-slot x 8KB LDS DMA ring, counted vmcnt(40); 4 MFMAs per row.
__global__ __launch_bounds__(64) void k_main(const float* __restrict__ T,
                                             const float* __restrict__ a0T,
                                             const float* __restrict__ D,
                                             float* __restrict__ tiles) {
  __shared__ float lds[DEPTH * 2048];  // 6 slots x 8192 B
  const int blk = blockIdx.x;
  const int m0 = blk * 64;
  const int l = (int)threadIdx.x;  // 0..63
  const int bo = l & 31;           // A row (b) / B col (o)
  const int g = l >> 5;            // k-group: k = 8*g + e

  // A-side D fragments: quarter p = D[bo][m0 + 16p + 8g + e]
  const float* dp = D + (size_t)bo * M3P2 + m0 + 8 * g;
  float df[4][8];
#pragma unroll
  for (int p = 0; p < 4; ++p) {
    *(float4*)(df[p])     = *(const float4*)(dp + 16 * p);
    *(float4*)(df[p] + 4) = *(const float4*)(dp + 16 * p + 4);
  }

  // a0 preload into registers
  float a0v[HP1];
#pragma unroll
  for (int i = 0; i < HP1; ++i) a0v[i] = a0T[i * 32 + bo];

  // Drain prologue loads BEFORE the DMA stream (pure vmcnt accounting).
  {
    float s = 0.f;
#pragma unroll
    for (int p = 0; p < 4; ++p)
#pragma unroll
      for (int e = 0; e < 8; ++e) s += df[p][e];
#pragma unroll
    for (int i = 0; i < HP1; ++i) s += a0v[i];
    asm volatile("" :: "v"(s) : "memory");
  }

  // Per-lane DMA source byte offsets: op q covers row floats [q*256+4l, +4)
  const int mrel = l >> 3;
  size_t src[8];
#pragma unroll
  for (int q = 0; q < 8; ++q) {
    const bool valid = (m0 + 8 * q + mrel) < M3;
    src[q] = valid ? ((size_t)(m0 * 32 + q * 256 + l * 4) * 4) : 0;
  }
  const char* Tb = (const char*)T;

#define ISSUE(row_, slot_)                                                    \
  {                                                                           \
    _Pragma("unroll")                                                         \
    for (int q = 0; q < 8; ++q) {                                             \
      __builtin_amdgcn_global_load_lds(                                       \
          (const __attribute__((address_space(1))) void*)(                    \
              Tb + (size_t)(row_)*TIB + src[q]),                              \
          (__attribute__((address_space(3))) void*)(                          \
              &lds[(slot_)*2048 + q * 256]),                                  \
          16, 0, 0);                                                          \
    }                                                                         \
  }

  // Fill the ring: 48 DMA ops in flight.
  ISSUE(0, 0) ISSUE(1, 1) ISSUE(2, 2) ISSUE(3, 3) ISSUE(4, 4) ISSUE(5, 5)

  f32x16 acc = {};

#define STEP(i_, vm_, doIssue_)                                               \
  {                                                                           \
    asm volatile("s_waitcnt vmcnt(" #vm_ ")" ::: "memory");                   \
    __builtin_amdgcn_sched_barrier(0);                                        \
    float tv[4][8];                                                           \
    _Pragma("unroll")                                                         \
    for (int p = 0; p < 4; ++p)                                               \
      _Pragma("unroll")                                                       \
      for (int e = 0; e < 8; ++e)                                             \
        tv[p][e] =                                                            \
            lds[((i_) % DEPTH) * 2048 + p * 512 + (8 * g + e) * 32 + bo];     \
    asm volatile("s_waitcnt lgkmcnt(0)" ::: "memory");                        \
    if (doIssue_) ISSUE((i_) + DEPTH, (i_) % DEPTH)                           \
    _Pragma("unroll")                                                         \
    for (int p = 0; p < 4; ++p) {                                             \
      bf16x8 af, bfr;                                                         \
      _Pragma("unroll")                                                       \
      for (int e = 0; e < 8; ++e) {                                           \
        af[e] = f2bf(a0v[i_] * df[p][e]);                                     \
        bfr[e] = f2bf(tv[p][e]);                                              \
      }                                                                       \
      acc = __builtin_amdgcn_mfma_f32_32x32x16_bf16(af, bfr, acc, 0, 0, 0);   \
    }                                                                         \
  }

  // 33 steps: steady vmcnt(40) while issuing (i<=26), then drain.
  STEP(0, 40, 1)  STEP(1, 40, 1)  STEP(2, 40, 1)  STEP(3, 40, 1)
  STEP(4, 40, 1)  STEP(5, 40, 1)  STEP(6, 40, 1)  STEP(7, 40, 1)
  STEP(8, 40, 1)  STEP(9, 40, 1)  STEP(10, 40, 1) STEP(11, 40, 1)
  STEP(12, 40, 1) STEP(13, 40, 1) STEP(14, 40, 1) STEP(15, 40, 1)
  STEP(16, 40, 1) STEP(17, 40, 1) STEP(18, 40, 1) STEP(19, 40, 1)
  STEP(20, 40, 1) STEP(21, 40, 1) STEP(22, 40, 1) STEP(23, 40, 1)
  STEP(24, 40, 1) STEP(25, 40, 1) STEP(26, 40, 1) STEP(27, 40, 0)
  STEP(28, 32, 0) STEP(29, 24, 0) STEP(30, 16, 0) STEP(31, 8, 0)
  STEP(32, 0, 0)
#undef STEP
#undef ISSUE

  // Accumulate into one of NT partial tiles (r19 epilogue verbatim).
  // C/D layout (m74/m101): col=lane&31, row=(r&3)+8*(r>>2)+4*(lane>>5)
  float* tp = tiles + (size_t)(blk & (NT - 1)) * 1024;
#pragma unroll
  for (int r = 0; r < 16; ++r) {
    const int brow = (r & 3) + 8 * (r >> 2) + 4 * g;
    atomicAdd(tp + brow * 32 + bo, acc[r]);
  }
}

// Final reduce (r19 verbatim): out[idx] = sum over NT tiles.
__global__ __launch_bounds__(256) void k_red(const float* __restrict__ tiles,
                                             float* __restrict__ out) {
  const int idx = blockIdx.x * 256 + (int)threadIdx.x;
  float s = 0.f;
  for (int t = 0; t < NT; ++t) s += tiles[(size_t)t * 1024 + idx];
  out[idx] = s;
}

extern "C" void kernel_launch(void* const* d_in, const int* in_sizes, int n_in,
                              void* d_out, int out_size, void* d_ws, size_t ws_size,
                              hipStream_t stream) {
  const float* nh = (const float*)d_in[0];  // [32,4,32]
  const float* T  = (const float*)d_in[1];  // [33,33,33,33,32]
  float* out = (float*)d_out;               // [32,32] fp32
  char* ws = (char*)d_ws;
  float* a0T   = (float*)(ws + OFF_A0T);
  float* D     = (float*)(ws + OFF_D);
  float* tiles = (float*)(ws + OFF_TILES);

  k_pre<<<dim3(141, 32), 256, 0, stream>>>(nh, a0T, D, tiles);
  k_main<<<NBLK, 64, 0, stream>>>(T, a0T, D, tiles);
  k_red<<<4, 256, 0, stream>>>(tiles, out);
}

// Round 22
// 39.221 us; speedup vs baseline: 1.4108x; 1.0174x over previous
//
#include <hip/hip_runtime.h>
#include <hip/hip_bf16.h>

// Problem constants
#define HSZ 32
#define HP1 33
#define M3 35937            // 33^3 (flattened j,k,l)
#define TI_STRIDE 1149984   // 33^3 * 32 floats (stride of T over i)
#define TIB ((size_t)TI_STRIDE * 4)
#define NBLK 1124           // one wave per block, 32 m's per block
#define NT 64               // partial output tiles (contention 1124/64 ~ 18)
#define DEPTH 6             // LDS ring slots (4KB each)
#define NHT 6144            // LDS float offset of staged nhT table
#define NHTG_FLOATS 4352    // staged floats (4224 real + zero pad)

// ws layout (bytes): nhTg @ 0 (17,408 B) ; tiles @ 32768 (262,144 B)
#define OFF_TILES 32768

typedef short bf16x8 __attribute__((ext_vector_type(8)));
typedef float f32x16 __attribute__((ext_vector_type(16)));

__device__ inline short f2bf(float f) {
  __hip_bfloat16 h = __float2bfloat16(f);  // RTNE; pairs into v_cvt_pk_bf16_f32
  return __builtin_bit_cast(short, h);
}

// Micro-prologue: 64 blocks zero tiles; block 64 builds transposed table
// nhTg[d*1056 + x*32 + b] (x=32 row = 1.0 bias; floats 4224.. zero pad).
__global__ __launch_bounds__(256) void k_pre(const float* __restrict__ nh,
                                             float* __restrict__ nhTg,
                                             float* __restrict__ tiles) {
  const int blk = (int)blockIdx.x;
  const int t = (int)threadIdx.x;
  if (blk < 64) {
    ((float4*)tiles)[blk * 256 + t] = make_float4(0.f, 0.f, 0.f, 0.f);
  } else {
    for (int x = t; x < NHTG_FLOATS; x += 256) {
      float v = 0.f;
      if (x < 4224) {
        const int d = x / 1056;
        const int rem = x - d * 1056;
        const int row = rem >> 5;
        const int b = rem & 31;
        v = (row < HSZ) ? nh[b * 128 + d * 32 + row] : 1.0f;
      }
      nhTg[x] = v;
    }
  }
}

// Main: one wave per block; block owns 32 m's. 6-slot x 4KB LDS DMA ring
// (r19 schedule). NEW: nhT staged to LDS via 17 DMA ops issued BEFORE the
// ring; df built in-wave from LDS (conflict-free, hidden under ring fill);
// a0 read per-step from LDS plane 0. D is gone entirely.
__global__ __launch_bounds__(64) void k_main(const float* __restrict__ T,
                                             const float* __restrict__ nhTg,
                                             float* __restrict__ tiles) {
  __shared__ float lds[DEPTH * 1024 + NHTG_FLOATS];  // 24KB ring + 17KB nhT
  const int blk = blockIdx.x;
  const int m0 = blk * 32;
  const int l = (int)threadIdx.x;  // 0..63
  const int bo = l & 31;           // A row (b) / B col (o)
  const int g = l >> 5;            // k-group: k = 8*g + e

  // Per-lane DMA source byte offsets: op q covers row floats [q*256+4l, +4)
  const int mrel = l >> 3;
  size_t src[4];
#pragma unroll
  for (int q = 0; q < 4; ++q) {
    const bool valid = (m0 + 8 * q + mrel) < M3;
    src[q] = valid ? ((size_t)(m0 * 32 + q * 256 + l * 4) * 4) : 0;
  }
  const char* Tb = (const char*)T;
  const char* Ng = (const char*)nhTg;

  // (1) Stage nhT -> LDS: 17 DMA ops (oldest in the vmcnt queue).
#pragma unroll
  for (int q = 0; q < 17; ++q) {
    __builtin_amdgcn_global_load_lds(
        (const __attribute__((address_space(1))) void*)(Ng + q * 1024 + l * 16),
        (__attribute__((address_space(3))) void*)(&lds[NHT + q * 256]),
        16, 0, 0);
  }

#define ISSUE(row_, slot_)                                                    \
  {                                                                           \
    _Pragma("unroll")                                                         \
    for (int q = 0; q < 4; ++q) {                                             \
      __builtin_amdgcn_global_load_lds(                                       \
          (const __attribute__((address_space(1))) void*)(                    \
              Tb + (size_t)(row_)*TIB + src[q]),                              \
          (__attribute__((address_space(3))) void*)(                          \
              &lds[(slot_)*1024 + q * 256]),                                  \
          16, 0, 0);                                                          \
    }                                                                         \
  }

  // (2) Fill the ring: 24 DMA ops in flight behind the 17 nhT ops.
  ISSUE(0, 0) ISSUE(1, 1) ISSUE(2, 2) ISSUE(3, 3) ISSUE(4, 4) ISSUE(5, 5)

  // (3) Wait for nhT only (ring stays in flight), then build df from LDS.
  asm volatile("s_waitcnt vmcnt(24)" ::: "memory");
  __builtin_amdgcn_sched_barrier(0);

  float df0[8], df1[8];
#pragma unroll
  for (int e = 0; e < 8; ++e) {
#pragma unroll
    for (int half = 0; half < 2; ++half) {
      const int m = m0 + 16 * half + 8 * g + e;
      const bool valid = m < M3;
      const int mc = valid ? m : (M3 - 1);
      const int j = mc / 1089;
      const int r = mc - j * 1089;
      const int kk = r / 33;
      const int ll = r - kk * 33;
      const float a1 = lds[NHT + 1056 + j * 32 + bo];
      const float a2 = lds[NHT + 2112 + kk * 32 + bo];
      const float a3 = lds[NHT + 3168 + ll * 32 + bo];
      const float v = valid ? (a1 * a2 * a3) : 0.0f;
      if (half == 0) df0[e] = v; else df1[e] = v;
    }
  }

  f32x16 acc = {};

#define STEP(i_, vm_, doIssue_)                                               \
  {                                                                           \
    asm volatile("s_waitcnt vmcnt(" #vm_ ")" ::: "memory");                   \
    __builtin_amdgcn_sched_barrier(0);                                        \
    float tv0[8], tv1[8];                                                     \
    const float a0 = lds[NHT + (i_)*32 + bo];                                 \
    _Pragma("unroll")                                                         \
    for (int e = 0; e < 8; ++e) {                                             \
      tv0[e] = lds[((i_) % DEPTH) * 1024 + (8 * g + e) * 32 + bo];            \
      tv1[e] = lds[((i_) % DEPTH) * 1024 + 512 + (8 * g + e) * 32 + bo];      \
    }                                                                         \
    asm volatile("s_waitcnt lgkmcnt(0)" ::: "memory");                        \
    if (doIssue_) ISSUE((i_) + DEPTH, (i_) % DEPTH)                           \
    bf16x8 af0, bf0, af1, bf1;                                                \
    _Pragma("unroll")                                                         \
    for (int e = 0; e < 8; ++e) {                                             \
      af0[e] = f2bf(a0 * df0[e]);                                             \
      bf0[e] = f2bf(tv0[e]);                                                  \
      af1[e] = f2bf(a0 * df1[e]);                                             \
      bf1[e] = f2bf(tv1[e]);                                                  \
    }                                                                         \
    acc = __builtin_amdgcn_mfma_f32_32x32x16_bf16(af0, bf0, acc, 0, 0, 0);    \
    acc = __builtin_amdgcn_mfma_f32_32x32x16_bf16(af1, bf1, acc, 0, 0, 0);    \
  }

  // 33 steps: steady vmcnt(20) while issuing (i<=26), then drain (r19).
  STEP(0, 20, 1)  STEP(1, 20, 1)  STEP(2, 20, 1)  STEP(3, 20, 1)
  STEP(4, 20, 1)  STEP(5, 20, 1)  STEP(6, 20, 1)  STEP(7, 20, 1)
  STEP(8, 20, 1)  STEP(9, 20, 1)  STEP(10, 20, 1) STEP(11, 20, 1)
  STEP(12, 20, 1) STEP(13, 20, 1) STEP(14, 20, 1) STEP(15, 20, 1)
  STEP(16, 20, 1) STEP(17, 20, 1) STEP(18, 20, 1) STEP(19, 20, 1)
  STEP(20, 20, 1) STEP(21, 20, 1) STEP(22, 20, 1) STEP(23, 20, 1)
  STEP(24, 20, 1) STEP(25, 20, 1) STEP(26, 20, 1) STEP(27, 20, 0)
  STEP(28, 16, 0) STEP(29, 12, 0) STEP(30, 8, 0)  STEP(31, 4, 0)
  STEP(32, 0, 0)
#undef STEP
#undef ISSUE

  // Accumulate into one of NT partial tiles (r19 epilogue verbatim).
  // C/D layout (m74/m101): col=lane&31, row=(r&3)+8*(r>>2)+4*(lane>>5)
  float* tp = tiles + (size_t)(blk & (NT - 1)) * 1024;
#pragma unroll
  for (int r = 0; r < 16; ++r) {
    const int brow = (r & 3) + 8 * (r >> 2) + 4 * g;
    atomicAdd(tp + brow * 32 + bo, acc[r]);
  }
}

// Final reduce (r19 verbatim): out[idx] = sum over NT tiles.
__global__ __launch_bounds__(256) void k_red(const float* __restrict__ tiles,
                                             float* __restrict__ out) {
  const int idx = blockIdx.x * 256 + (int)threadIdx.x;
  float s = 0.f;
  for (int t = 0; t < NT; ++t) s += tiles[(size_t)t * 1024 + idx];
  out[idx] = s;
}

extern "C" void kernel_launch(void* const* d_in, const int* in_sizes, int n_in,
                              void* d_out, int out_size, void* d_ws, size_t ws_size,
                              hipStream_t stream) {
  const float* nh = (const float*)d_in[0];  // [32,4,32]
  const float* T  = (const float*)d_in[1];  // [33,33,33,33,32]
  float* out = (float*)d_out;               // [32,32] fp32
  char* ws = (char*)d_ws;
  float* nhTg  = (float*)ws;
  float* tiles = (float*)(ws + OFF_TILES);

  k_pre<<<65, 256, 0, stream>>>(nh, nhTg, tiles);
  k_main<<<NBLK, 64, 0, stream>>>(T, nhTg, tiles);
  k_red<<<4, 256, 0, stream>>>(tiles, out);
}

// Round 23
// 39.191 us; speedup vs baseline: 1.4119x; 1.0008x over previous
//
#include <hip/hip_runtime.h>
#include <hip/hip_bf16.h>

// Problem constants
#define HSZ 32
#define HP1 33
#define M3 35937            // 33^3 (flattened j,k,l)
#define TI_STRIDE 1149984   // 33^3 * 32 floats (stride of T over i)
#define TIB ((size_t)TI_STRIDE * 4)
#define NBLK 1124           // one wave per block, 32 m's per block
#define NT 64               // partial output tiles (contention 1124/64 ~ 18)
#define DEPTH 6             // LDS ring slots (4KB each)
#define NHT 6144            // LDS float offset of staged nhT table
#define NHTG_FLOATS 4352    // staged floats (4224 real + zero pad)

// ws layout (bytes): nhTg @ 0 (17,408 B) ; tiles @ 32768 (262,144 B)
#define OFF_TILES 32768

typedef short bf16x8 __attribute__((ext_vector_type(8)));
typedef float f32x16 __attribute__((ext_vector_type(16)));

__device__ inline short f2bf(float f) {
  __hip_bfloat16 h = __float2bfloat16(f);  // RTNE; pairs into v_cvt_pk_bf16_f32
  return __builtin_bit_cast(short, h);
}

// Micro-prologue (r22 verbatim): 64 blocks zero tiles; block 64 builds nhTg.
__global__ __launch_bounds__(256) void k_pre(const float* __restrict__ nh,
                                             float* __restrict__ nhTg,
                                             float* __restrict__ tiles) {
  const int blk = (int)blockIdx.x;
  const int t = (int)threadIdx.x;
  if (blk < 64) {
    ((float4*)tiles)[blk * 256 + t] = make_float4(0.f, 0.f, 0.f, 0.f);
  } else {
    for (int x = t; x < NHTG_FLOATS; x += 256) {
      float v = 0.f;
      if (x < 4224) {
        const int d = x / 1056;
        const int rem = x - d * 1056;
        const int row = rem >> 5;
        const int b = rem & 31;
        v = (row < HSZ) ? nh[b * 128 + d * 32 + row] : 1.0f;
      }
      nhTg[x] = v;
    }
  }
}

// Main (r22 with ONE change): lgkmcnt(0)+ISSUE moved AFTER the MFMAs, so
// the ~120cy LDS read latency hides under the cvt/MFMA stream instead of
// being exposed between the reads and the DMA reissue every step.
__global__ __launch_bounds__(64) void k_main(const float* __restrict__ T,
                                             const float* __restrict__ nhTg,
                                             float* __restrict__ tiles) {
  __shared__ float lds[DEPTH * 1024 + NHTG_FLOATS];  // 24KB ring + 17KB nhT
  const int blk = blockIdx.x;
  const int m0 = blk * 32;
  const int l = (int)threadIdx.x;  // 0..63
  const int bo = l & 31;           // A row (b) / B col (o)
  const int g = l >> 5;            // k-group: k = 8*g + e

  // Per-lane DMA source byte offsets: op q covers row floats [q*256+4l, +4)
  const int mrel = l >> 3;
  size_t src[4];
#pragma unroll
  for (int q = 0; q < 4; ++q) {
    const bool valid = (m0 + 8 * q + mrel) < M3;
    src[q] = valid ? ((size_t)(m0 * 32 + q * 256 + l * 4) * 4) : 0;
  }
  const char* Tb = (const char*)T;
  const char* Ng = (const char*)nhTg;

  // (1) Stage nhT -> LDS: 17 DMA ops (oldest in the vmcnt queue).
#pragma unroll
  for (int q = 0; q < 17; ++q) {
    __builtin_amdgcn_global_load_lds(
        (const __attribute__((address_space(1))) void*)(Ng + q * 1024 + l * 16),
        (__attribute__((address_space(3))) void*)(&lds[NHT + q * 256]),
        16, 0, 0);
  }

#define ISSUE(row_, slot_)                                                    \
  {                                                                           \
    _Pragma("unroll")                                                         \
    for (int q = 0; q < 4; ++q) {                                             \
      __builtin_amdgcn_global_load_lds(                                       \
          (const __attribute__((address_space(1))) void*)(                    \
              Tb + (size_t)(row_)*TIB + src[q]),                              \
          (__attribute__((address_space(3))) void*)(                          \
              &lds[(slot_)*1024 + q * 256]),                                  \
          16, 0, 0);                                                          \
    }                                                                         \
  }

  // (2) Fill the ring: 24 DMA ops in flight behind the 17 nhT ops.
  ISSUE(0, 0) ISSUE(1, 1) ISSUE(2, 2) ISSUE(3, 3) ISSUE(4, 4) ISSUE(5, 5)

  // (3) Wait for nhT only (ring stays in flight), then build df from LDS.
  asm volatile("s_waitcnt vmcnt(24)" ::: "memory");
  __builtin_amdgcn_sched_barrier(0);

  float df0[8], df1[8];
#pragma unroll
  for (int e = 0; e < 8; ++e) {
#pragma unroll
    for (int half = 0; half < 2; ++half) {
      const int m = m0 + 16 * half + 8 * g + e;
      const bool valid = m < M3;
      const int mc = valid ? m : (M3 - 1);
      const int j = mc / 1089;
      const int r = mc - j * 1089;
      const int kk = r / 33;
      const int ll = r - kk * 33;
      const float a1 = lds[NHT + 1056 + j * 32 + bo];
      const float a2 = lds[NHT + 2112 + kk * 32 + bo];
      const float a3 = lds[NHT + 3168 + ll * 32 + bo];
      const float v = valid ? (a1 * a2 * a3) : 0.0f;
      if (half == 0) df0[e] = v; else df1[e] = v;
    }
  }

  f32x16 acc = {};

#define STEP(i_, vm_, doIssue_)                                               \
  {                                                                           \
    asm volatile("s_waitcnt vmcnt(" #vm_ ")" ::: "memory");                   \
    __builtin_amdgcn_sched_barrier(0);                                        \
    float tv0[8], tv1[8];                                                     \
    const float a0 = lds[NHT + (i_)*32 + bo];                                 \
    _Pragma("unroll")                                                         \
    for (int e = 0; e < 8; ++e) {                                             \
      tv0[e] = lds[((i_) % DEPTH) * 1024 + (8 * g + e) * 32 + bo];            \
      tv1[e] = lds[((i_) % DEPTH) * 1024 + 512 + (8 * g + e) * 32 + bo];      \
    }                                                                         \
    bf16x8 af0, bf0, af1, bf1;                                                \
    _Pragma("unroll")                                                         \
    for (int e = 0; e < 8; ++e) {                                             \
      af0[e] = f2bf(a0 * df0[e]);                                             \
      bf0[e] = f2bf(tv0[e]);                                                  \
      af1[e] = f2bf(a0 * df1[e]);                                             \
      bf1[e] = f2bf(tv1[e]);                                                  \
    }                                                                         \
    acc = __builtin_amdgcn_mfma_f32_32x32x16_bf16(af0, bf0, acc, 0, 0, 0);    \
    acc = __builtin_amdgcn_mfma_f32_32x32x16_bf16(af1, bf1, acc, 0, 0, 0);    \
    if (doIssue_) {                                                           \
      asm volatile("s_waitcnt lgkmcnt(0)" ::: "memory");                      \
      __builtin_amdgcn_sched_barrier(0);                                      \
      ISSUE((i_) + DEPTH, (i_) % DEPTH)                                       \
    }                                                                         \
  }

  // 33 steps: steady vmcnt(20) while issuing (i<=26), then drain (r19).
  STEP(0, 20, 1)  STEP(1, 20, 1)  STEP(2, 20, 1)  STEP(3, 20, 1)
  STEP(4, 20, 1)  STEP(5, 20, 1)  STEP(6, 20, 1)  STEP(7, 20, 1)
  STEP(8, 20, 1)  STEP(9, 20, 1)  STEP(10, 20, 1) STEP(11, 20, 1)
  STEP(12, 20, 1) STEP(13, 20, 1) STEP(14, 20, 1) STEP(15, 20, 1)
  STEP(16, 20, 1) STEP(17, 20, 1) STEP(18, 20, 1) STEP(19, 20, 1)
  STEP(20, 20, 1) STEP(21, 20, 1) STEP(22, 20, 1) STEP(23, 20, 1)
  STEP(24, 20, 1) STEP(25, 20, 1) STEP(26, 20, 1) STEP(27, 20, 0)
  STEP(28, 16, 0) STEP(29, 12, 0) STEP(30, 8, 0)  STEP(31, 4, 0)
  STEP(32, 0, 0)
#undef STEP
#undef ISSUE

  // Accumulate into one of NT partial tiles (r19 epilogue verbatim).
  // C/D layout (m74/m101): col=lane&31, row=(r&3)+8*(r>>2)+4*(lane>>5)
  float* tp = tiles + (size_t)(blk & (NT - 1)) * 1024;
#pragma unroll
  for (int r = 0; r < 16; ++r) {
    const int brow = (r & 3) + 8 * (r >> 2) + 4 * g;
    atomicAdd(tp + brow * 32 + bo, acc[r]);
  }
}

// Final reduce (r19 verbatim): out[idx] = sum over NT tiles.
__global__ __launch_bounds__(256) void k_red(const float* __restrict__ tiles,
                                             float* __restrict__ out) {
  const int idx = blockIdx.x * 256 + (int)threadIdx.x;
  float s = 0.f;
  for (int t = 0; t < NT; ++t) s += tiles[(size_t)t * 1024 + idx];
  out[idx] = s;
}

extern "C" void kernel_launch(void* const* d_in, const int* in_sizes, int n_in,
                              void* d_out, int out_size, void* d_ws, size_t ws_size,
                              hipStream_t stream) {
  const float* nh = (const float*)d_in[0];  // [32,4,32]
  const float* T  = (const float*)d_in[1];  // [33,33,33,33,32]
  float* out = (float*)d_out;               // [32,32] fp32
  char* ws = (char*)d_ws;
  float* nhTg  = (float*)ws;
  float* tiles = (float*)(ws + OFF_TILES);

  k_pre<<<65, 256, 0, stream>>>(nh, nhTg, tiles);
  k_main<<<NBLK, 64, 0, stream>>>(T, nhTg, tiles);
  k_red<<<4, 256, 0, stream>>>(tiles, out);
}